// Round 1
// baseline (1084.995 us; speedup 1.0000x reference)
//
#include <hip/hip_runtime.h>

#define N_SP 3136   // H*W = 56*56
#define C_CH 256
#define CQ   32
#define NB   4
#define TI   8
// 1 / (exp(sqrt(3))*sqrt(3136/256) + 2*sqrt(6))
#define INV_BOUND 0.04051569f

typedef unsigned int  uint_t;
typedef unsigned short ushort_t;

__device__ __forceinline__ float bf_lo(uint_t u) { return __builtin_bit_cast(float, u << 16); }
__device__ __forceinline__ float bf_hi(uint_t u) { return __builtin_bit_cast(float, u & 0xffff0000u); }
__device__ __forceinline__ ushort_t f2b(float f) {
    uint_t u = __builtin_bit_cast(uint_t, f);
    u += 0x7fffu + ((u >> 16) & 1u);   // round-to-nearest-even
    return (ushort_t)(u >> 16);
}

// ---------------------------------------------------------------------------
// scale = 1 / (||Wq||_F * max(max_col ||Wk[:,c]||, max_col ||Wv[:,c]||))
// ---------------------------------------------------------------------------
__global__ __launch_bounds__(256) void norm_kernel(
    const float* __restrict__ Wq, const float* __restrict__ Wk,
    const float* __restrict__ Wv, float* __restrict__ scale_out)
{
    __shared__ float red[256];
    const int t = threadIdx.x;

    float u2 = 0.f;
    for (int i = t; i < CQ * C_CH; i += 256) { float w = Wq[i]; u2 += w * w; }
    red[t] = u2; __syncthreads();
    #pragma unroll
    for (int s = 128; s > 0; s >>= 1) { if (t < s) red[t] += red[t + s]; __syncthreads(); }
    float u2t = red[0]; __syncthreads();

    float vn2 = 0.f;
    for (int o = 0; o < CQ; ++o)   { float w = Wk[o * C_CH + t]; vn2 += w * w; }
    float wn2 = 0.f;
    for (int o = 0; o < C_CH; ++o) { float w = Wv[o * C_CH + t]; wn2 += w * w; }
    red[t] = fmaxf(vn2, wn2); __syncthreads();
    #pragma unroll
    for (int s = 128; s > 0; s >>= 1) { if (t < s) red[t] = fmaxf(red[t], red[t + s]); __syncthreads(); }
    if (t == 0) scale_out[0] = 1.0f / (sqrtf(u2t) * sqrtf(red[0]));
}

// ---------------------------------------------------------------------------
// q/k/v 1x1 convs: one block per (b, 64-col tile of N). x panel staged in LDS.
// Rows (32 q + 32 k + 256 v = 320) split 80/wave; weights scalarized.
// ---------------------------------------------------------------------------
__global__ __launch_bounds__(256) void qkv_kernel(
    const float* __restrict__ x,
    const float* __restrict__ Wq, const float* __restrict__ bq,
    const float* __restrict__ Wk, const float* __restrict__ bk,
    const float* __restrict__ Wv, const float* __restrict__ bv,
    float* __restrict__ q, float* __restrict__ k, float* __restrict__ v)
{
    __shared__ float xs[C_CH][64];                  // 64 KB
    const int t  = threadIdx.x;
    const int b  = blockIdx.x / (N_SP / 64);
    const int n0 = (blockIdx.x % (N_SP / 64)) * 64;

    for (int idx = t; idx < C_CH * 64; idx += 256) {
        int c = idx >> 6, nn = idx & 63;
        xs[c][nn] = x[((size_t)b * C_CH + c) * N_SP + n0 + nn];
    }
    __syncthreads();

    const int nn = t & 63;
    const int og = __builtin_amdgcn_readfirstlane(t >> 6);   // wave id, force SGPR

    for (int rc = 0; rc < 80; rc += 8) {
        int row0 = og * 80 + rc;                    // chunk never spans q/k/v boundary
        const float* W; const float* bias; float* dst; int r0; int Rt;
        if (row0 < 32)      { W = Wq; bias = bq; dst = q; r0 = row0;      Rt = CQ;   }
        else if (row0 < 64) { W = Wk; bias = bk; dst = k; r0 = row0 - 32; Rt = CQ;   }
        else                { W = Wv; bias = bv; dst = v; r0 = row0 - 64; Rt = C_CH; }

        float acc[8];
        #pragma unroll
        for (int m = 0; m < 8; ++m) acc[m] = bias[r0 + m];
        #pragma unroll 4
        for (int c = 0; c < C_CH; ++c) {
            float xv = xs[c][nn];                   // 1 ds_read feeds 8 FMAs
            #pragma unroll
            for (int m = 0; m < 8; ++m) acc[m] += W[(r0 + m) * C_CH + c] * xv;
        }
        #pragma unroll
        for (int m = 0; m < 8; ++m)
            dst[((size_t)b * Rt + r0 + m) * N_SP + n0 + nn] = acc[m];
    }
}

// ---------------------------------------------------------------------------
// Attention: one block per (b, TI=8 query rows). Whole score rows in LDS (bf16),
// exact softmax, then PV with thread-per-channel (c = threadIdx.x).
// ---------------------------------------------------------------------------
__global__ __launch_bounds__(256) void attn_kernel(
    const float* __restrict__ qg, const float* __restrict__ kg,
    const float* __restrict__ vg, const float* __restrict__ x,
    const float* __restrict__ gamma_p, const float* __restrict__ scale_p,
    float* __restrict__ out)
{
    __shared__ __align__(16) ushort_t sc[TI][N_SP]; // 50176 B (bf16 scores -> p)
    __shared__ float ql[TI][CQ];
    __shared__ float red[256];
    __shared__ float rowsum[TI];

    const int t  = threadIdx.x;
    const int b  = blockIdx.x / (N_SP / TI);
    const int i0 = (blockIdx.x % (N_SP / TI)) * TI;
    const float scale = scale_p[0];

    {   // q tile, scale folded in
        int r = t & (TI - 1);
        int cq = t >> 3;
        ql[r][cq] = qg[((size_t)b * CQ + cq) * N_SP + i0 + r] * scale;
    }
    __syncthreads();

    // phase 1: energy rows s[r][j] = scale * <q_i, k_j>
    for (int j = t; j < N_SP; j += 256) {
        float acc[TI];
        #pragma unroll
        for (int r = 0; r < TI; ++r) acc[r] = 0.f;
        #pragma unroll 4
        for (int cq = 0; cq < CQ; ++cq) {
            float kv = kg[((size_t)b * CQ + cq) * N_SP + j];
            #pragma unroll
            for (int r = 0; r < TI; ++r) acc[r] += ql[r][cq] * kv;
        }
        #pragma unroll
        for (int r = 0; r < TI; ++r) sc[r][j] = f2b(acc[r]);
    }
    __syncthreads();

    // phase 2: exact softmax per row (p stored unnormalized, denom kept)
    for (int r = 0; r < TI; ++r) {
        float mx = -1e30f;
        for (int j = t; j < N_SP; j += 256)
            mx = fmaxf(mx, bf_lo((uint_t)sc[r][j]));
        red[t] = mx; __syncthreads();
        #pragma unroll
        for (int s = 128; s > 0; s >>= 1) { if (t < s) red[t] = fmaxf(red[t], red[t + s]); __syncthreads(); }
        mx = red[0]; __syncthreads();

        float sum = 0.f;
        for (int j = t; j < N_SP; j += 256) {
            float p = __expf(bf_lo((uint_t)sc[r][j]) - mx);
            sum += p;
            sc[r][j] = f2b(p);
        }
        red[t] = sum; __syncthreads();
        #pragma unroll
        for (int s = 128; s > 0; s >>= 1) { if (t < s) red[t] += red[t + s]; __syncthreads(); }
        if (t == 0) rowsum[r] = red[0];
        __syncthreads();
    }

    // phase 3: out[c][i0+r] = sum_j p[r][j] * v[c][j]; c = t
    float2 acc2[TI];
    #pragma unroll
    for (int r = 0; r < TI; ++r) acc2[r] = make_float2(0.f, 0.f);
    const float* vrow = vg + ((size_t)b * C_CH + t) * N_SP;
    for (int j = 0; j < N_SP; j += 8) {
        float4 va = *(const float4*)(vrow + j);
        float4 vb = *(const float4*)(vrow + j + 4);
        #pragma unroll
        for (int r = 0; r < TI; ++r) {
            uint4 pu = *(const uint4*)&sc[r][j];    // 8 bf16 p values, broadcast
            acc2[r].x += bf_lo(pu.x) * va.x;  acc2[r].y += bf_hi(pu.x) * va.y;
            acc2[r].x += bf_lo(pu.y) * va.z;  acc2[r].y += bf_hi(pu.y) * va.w;
            acc2[r].x += bf_lo(pu.z) * vb.x;  acc2[r].y += bf_hi(pu.z) * vb.y;
            acc2[r].x += bf_lo(pu.w) * vb.z;  acc2[r].y += bf_hi(pu.w) * vb.w;
        }
    }

    const float g = gamma_p[0];
    #pragma unroll
    for (int r = 0; r < TI; ++r) {
        float o = (acc2[r].x + acc2[r].y) / rowsum[r] * INV_BOUND;
        size_t idx = ((size_t)b * C_CH + t) * N_SP + i0 + r;
        out[idx] = g * o + x[idx];
    }
}

// ---------------------------------------------------------------------------
extern "C" void kernel_launch(void* const* d_in, const int* in_sizes, int n_in,
                              void* d_out, int out_size, void* d_ws, size_t ws_size,
                              hipStream_t stream)
{
    const float* x  = (const float*)d_in[0];
    const float* Wq = (const float*)d_in[1];
    const float* bq = (const float*)d_in[2];
    const float* Wk = (const float*)d_in[3];
    const float* bk = (const float*)d_in[4];
    const float* Wv = (const float*)d_in[5];
    const float* bv = (const float*)d_in[6];
    const float* gm = (const float*)d_in[7];
    float* out = (float*)d_out;
    float* ws  = (float*)d_ws;

    // ws layout (floats): [0..63] scale pad; q (B*CQ*N); k (B*CQ*N); v (B*C*N)
    // total ~16.06 MB
    float* scale = ws;
    float* q = ws + 64;
    float* k = q + (size_t)NB * CQ * N_SP;
    float* v = k + (size_t)NB * CQ * N_SP;

    norm_kernel<<<1, 256, 0, stream>>>(Wq, Wk, Wv, scale);
    qkv_kernel<<<NB * (N_SP / 64), 256, 0, stream>>>(x, Wq, bq, Wk, bk, Wv, bv, q, k, v);
    attn_kernel<<<NB * (N_SP / TI), 256, 0, stream>>>(q, k, v, x, gm, scale, out);
}

// Round 2
// 166.238 us; speedup vs baseline: 6.5268x; 6.5268x over previous
//
#include <hip/hip_runtime.h>

#define N_SP 3136   // H*W
#define C_CH 256
#define CQ   32
#define NB   4
// 1 / (exp(sqrt(3))*sqrt(3136/256) + 2*sqrt(6))
#define INV_BOUND 0.04051569f

typedef __attribute__((ext_vector_type(8))) short bf16x8;
typedef __attribute__((ext_vector_type(4))) float f32x4;
typedef unsigned short u16;
typedef unsigned int   u32;

#define MFMA16(a,b,c) __builtin_amdgcn_mfma_f32_16x16x32_bf16(a,b,c,0,0,0)

__device__ __forceinline__ u16 f2b(float f) {
    u32 u = __builtin_bit_cast(u32, f);
    u += 0x7fffu + ((u >> 16) & 1u);   // RTNE
    return (u16)(u >> 16);
}

// ---------------------------------------------------------------------------
// scale = 1 / (||Wq||_F * max(max_col ||Wk[:,c]||, max_col ||Wv[:,c]||))
// ---------------------------------------------------------------------------
__global__ __launch_bounds__(256) void norm_kernel(
    const float* __restrict__ Wq, const float* __restrict__ Wk,
    const float* __restrict__ Wv, float* __restrict__ scale_out)
{
    __shared__ float red[256];
    const int t = threadIdx.x;

    float u2 = 0.f;
    for (int i = t; i < CQ * C_CH; i += 256) { float w = Wq[i]; u2 += w * w; }
    red[t] = u2; __syncthreads();
    #pragma unroll
    for (int s = 128; s > 0; s >>= 1) { if (t < s) red[t] += red[t + s]; __syncthreads(); }
    float u2t = red[0]; __syncthreads();

    float vn2 = 0.f;
    for (int o = 0; o < CQ; ++o)   { float w = Wk[o * C_CH + t]; vn2 += w * w; }
    float wn2 = 0.f;
    for (int o = 0; o < C_CH; ++o) { float w = Wv[o * C_CH + t]; wn2 += w * w; }
    red[t] = fmaxf(vn2, wn2); __syncthreads();
    #pragma unroll
    for (int s = 128; s > 0; s >>= 1) { if (t < s) red[t] = fmaxf(red[t], red[t + s]); __syncthreads(); }
    if (t == 0) scale_out[0] = 1.0f / (sqrtf(u2t) * sqrtf(red[0]));
}

// ---------------------------------------------------------------------------
// W f32 -> bf16 (flat, 4 elems/thread). 80 blocks x 256 = 20480 quads exact.
// ---------------------------------------------------------------------------
__global__ __launch_bounds__(256) void wcvt_kernel(
    const float* __restrict__ Wq, const float* __restrict__ Wk,
    const float* __restrict__ Wv, u16* __restrict__ Wqb,
    u16* __restrict__ Wkb, u16* __restrict__ Wvb)
{
    int idx = blockIdx.x * 256 + threadIdx.x;
    const float* src; u16* dst; int off;
    if (idx < 2048)      { src = Wq; dst = Wqb; off = idx; }
    else if (idx < 4096) { src = Wk; dst = Wkb; off = idx - 2048; }
    else                 { src = Wv; dst = Wvb; off = idx - 4096; }
    float4 v = *(const float4*)(src + off * 4);
    ushort4 o; o.x = f2b(v.x); o.y = f2b(v.y); o.z = f2b(v.z); o.w = f2b(v.w);
    *(ushort4*)(dst + off * 4) = o;
}

// ---------------------------------------------------------------------------
// xT[b][n][c] = bf16(x[b][c][n]) — 64x64 LDS tile transpose. 784 blocks.
// ---------------------------------------------------------------------------
__global__ __launch_bounds__(256) void xt_kernel(
    const float* __restrict__ x, u16* __restrict__ xT)
{
    __shared__ float tile[64][65];
    const int t = threadIdx.x;
    const int ct = blockIdx.x & 3;
    const int nt = (blockIdx.x >> 2) % 49;
    const int b  = blockIdx.x / 196;
    const int c0 = ct * 64, n0 = nt * 64;

    const int cc = t >> 4, nn4 = (t & 15) * 4;
    #pragma unroll
    for (int i = 0; i < 4; ++i) {
        int cl = cc + i * 16;
        float4 v = *(const float4*)(x + (size_t)(b * C_CH + c0 + cl) * N_SP + n0 + nn4);
        tile[cl][nn4] = v.x; tile[cl][nn4 + 1] = v.y;
        tile[cl][nn4 + 2] = v.z; tile[cl][nn4 + 3] = v.w;
    }
    __syncthreads();
    const int c4 = (t & 15) * 4, nn = t >> 4;
    #pragma unroll
    for (int i = 0; i < 4; ++i) {
        int nl = nn + i * 16;
        ushort4 o;
        o.x = f2b(tile[c4 + 0][nl]); o.y = f2b(tile[c4 + 1][nl]);
        o.z = f2b(tile[c4 + 2][nl]); o.w = f2b(tile[c4 + 3][nl]);
        *(ushort4*)(xT + (size_t)(b * N_SP + n0 + nl) * C_CH + c0 + c4) = o;
    }
}

// ---------------------------------------------------------------------------
// qkv via MFMA: out rows = W rows, cols = n. Per block: 64 n-cols, wave = 16 n.
// Emits qT[b][n][32] (scale folded), kT[b][n][32], V[b][c][n] — all bf16.
// ---------------------------------------------------------------------------
__global__ __launch_bounds__(256) void qkv_mfma(
    const u16* __restrict__ xT, const u16* __restrict__ Wqb,
    const u16* __restrict__ Wkb, const u16* __restrict__ Wvb,
    const float* __restrict__ bq, const float* __restrict__ bk,
    const float* __restrict__ bv, const float* __restrict__ scale_p,
    u16* __restrict__ qT, u16* __restrict__ kT, u16* __restrict__ Vb)
{
    const int t = threadIdx.x;
    const int b = blockIdx.x / 49, nt = blockIdx.x % 49;
    const int w = t >> 6, li = t & 15, g = (t >> 4) & 3;
    const int n = nt * 64 + w * 16 + li;
    const float sc = scale_p[0];
    const f32x4 zero = {0.f, 0.f, 0.f, 0.f};

    bf16x8 xf[8];
    #pragma unroll
    for (int ks = 0; ks < 8; ++ks)
        xf[ks] = *(const bf16x8*)(xT + (size_t)(b * N_SP + n) * C_CH + ks * 32 + 8 * g);

    // ---- Q (rows 0..31) and K ----
    {
        f32x4 aq0 = zero, aq1 = zero, ak0 = zero, ak1 = zero;
        #pragma unroll
        for (int ks = 0; ks < 8; ++ks) {
            bf16x8 w0 = *(const bf16x8*)(Wqb + (li)      * C_CH + ks * 32 + 8 * g);
            bf16x8 w1 = *(const bf16x8*)(Wqb + (16 + li) * C_CH + ks * 32 + 8 * g);
            bf16x8 w2 = *(const bf16x8*)(Wkb + (li)      * C_CH + ks * 32 + 8 * g);
            bf16x8 w3 = *(const bf16x8*)(Wkb + (16 + li) * C_CH + ks * 32 + 8 * g);
            aq0 = MFMA16(w0, xf[ks], aq0);
            aq1 = MFMA16(w1, xf[ks], aq1);
            ak0 = MFMA16(w2, xf[ks], ak0);
            ak1 = MFMA16(w3, xf[ks], ak1);
        }
        f32x4 bq0 = *(const f32x4*)(bq + 4 * g);
        f32x4 bq1 = *(const f32x4*)(bq + 16 + 4 * g);
        f32x4 bk0 = *(const f32x4*)(bk + 4 * g);
        f32x4 bk1 = *(const f32x4*)(bk + 16 + 4 * g);
        ushort4 s0, s1;
        s0.x = f2b((aq0[0] + bq0[0]) * sc); s0.y = f2b((aq0[1] + bq0[1]) * sc);
        s0.z = f2b((aq0[2] + bq0[2]) * sc); s0.w = f2b((aq0[3] + bq0[3]) * sc);
        s1.x = f2b((aq1[0] + bq1[0]) * sc); s1.y = f2b((aq1[1] + bq1[1]) * sc);
        s1.z = f2b((aq1[2] + bq1[2]) * sc); s1.w = f2b((aq1[3] + bq1[3]) * sc);
        *(ushort4*)(qT + (size_t)(b * N_SP + n) * CQ + 4 * g)      = s0;
        *(ushort4*)(qT + (size_t)(b * N_SP + n) * CQ + 16 + 4 * g) = s1;
        s0.x = f2b(ak0[0] + bk0[0]); s0.y = f2b(ak0[1] + bk0[1]);
        s0.z = f2b(ak0[2] + bk0[2]); s0.w = f2b(ak0[3] + bk0[3]);
        s1.x = f2b(ak1[0] + bk1[0]); s1.y = f2b(ak1[1] + bk1[1]);
        s1.z = f2b(ak1[2] + bk1[2]); s1.w = f2b(ak1[3] + bk1[3]);
        *(ushort4*)(kT + (size_t)(b * N_SP + n) * CQ + 4 * g)      = s0;
        *(ushort4*)(kT + (size_t)(b * N_SP + n) * CQ + 16 + 4 * g) = s1;
    }

    // ---- V (rows 0..255), pairs of 16-row frags ----
    #pragma unroll
    for (int fp = 0; fp < 16; fp += 2) {
        f32x4 a0 = zero, a1 = zero;
        #pragma unroll
        for (int ks = 0; ks < 8; ++ks) {
            bf16x8 w0 = *(const bf16x8*)(Wvb + (fp * 16 + li)       * C_CH + ks * 32 + 8 * g);
            bf16x8 w1 = *(const bf16x8*)(Wvb + ((fp + 1) * 16 + li) * C_CH + ks * 32 + 8 * g);
            a0 = MFMA16(w0, xf[ks], a0);
            a1 = MFMA16(w1, xf[ks], a1);
        }
        f32x4 b0 = *(const f32x4*)(bv + fp * 16 + 4 * g);
        f32x4 b1 = *(const f32x4*)(bv + fp * 16 + 16 + 4 * g);
        #pragma unroll
        for (int r = 0; r < 4; ++r) {
            Vb[(size_t)(b * C_CH + fp * 16 + 4 * g + r) * N_SP + n]        = f2b(a0[r] + b0[r]);
            Vb[(size_t)(b * C_CH + (fp + 1) * 16 + 4 * g + r) * N_SP + n]  = f2b(a1[r] + b1[r]);
        }
    }
}

// ---------------------------------------------------------------------------
// Flash attention, 2-pass (exact row max, no online rescale).
// Block = 32 queries x full 256 channels; 4 waves (wave: 16-col S slice, 64-ch
// PV slice). P round-trips through XOR-swizzled LDS (dbuf, 1 barrier/tile).
// ---------------------------------------------------------------------------
__global__ __launch_bounds__(256) void attn_mfma(
    const u16* __restrict__ qT, const u16* __restrict__ kT,
    const u16* __restrict__ Vb, const float* __restrict__ x,
    const float* __restrict__ gamma_p, float* __restrict__ out)
{
    __shared__ __align__(16) unsigned char P[2][4096];
    __shared__ float red_part[4][32];
    __shared__ __align__(16) float red_final[32];

    const int t = threadIdx.x;
    const int w = t >> 6, li = t & 15, g = (t >> 4) & 3;
    const int xcd = blockIdx.x & 7, tt = blockIdx.x >> 3;   // 392 = 49*8 bijective
    const int b  = xcd >> 1;
    const int i0 = ((xcd & 1) * 49 + tt) * 32;

    const u16* qTb = qT + (size_t)b * N_SP * CQ;
    const u16* kTb = kT + (size_t)b * N_SP * CQ;
    const u16* Vbb = Vb + (size_t)b * C_CH * N_SP;
    const f32x4 zero = {0.f, 0.f, 0.f, 0.f};

    const bf16x8 qf0 = *(const bf16x8*)(qTb + (size_t)(i0 + li) * CQ + 8 * g);
    const bf16x8 qf1 = *(const bf16x8*)(qTb + (size_t)(i0 + 16 + li) * CQ + 8 * g);

    // ---- pass 1: exact row max ----
    f32x4 m0 = {-1e30f, -1e30f, -1e30f, -1e30f}, m1 = m0;
    for (int it = 0; it < 49; ++it) {
        bf16x8 kf = *(const bf16x8*)(kTb + (size_t)(it * 64 + w * 16 + li) * CQ + 8 * g);
        f32x4 s0 = MFMA16(qf0, kf, zero);
        f32x4 s1 = MFMA16(qf1, kf, zero);
        #pragma unroll
        for (int r = 0; r < 4; ++r) { m0[r] = fmaxf(m0[r], s0[r]); m1[r] = fmaxf(m1[r], s1[r]); }
    }
    #pragma unroll
    for (int d = 1; d < 16; d <<= 1) {
        #pragma unroll
        for (int r = 0; r < 4; ++r) {
            m0[r] = fmaxf(m0[r], __shfl_xor(m0[r], d));
            m1[r] = fmaxf(m1[r], __shfl_xor(m1[r], d));
        }
    }
    if (li == 0) {
        #pragma unroll
        for (int r = 0; r < 4; ++r) {
            red_part[w][4 * g + r]      = m0[r];
            red_part[w][16 + 4 * g + r] = m1[r];
        }
    }
    __syncthreads();
    if (t < 32) red_final[t] = fmaxf(fmaxf(red_part[0][t], red_part[1][t]),
                                     fmaxf(red_part[2][t], red_part[3][t]));
    __syncthreads();
    const f32x4 mr0 = *(const f32x4*)(red_final + 4 * g);
    const f32x4 mr1 = *(const f32x4*)(red_final + 16 + 4 * g);

    // ---- pass 2: P = exp(S - m), PV accumulate ----
    f32x4 acc[2][4];
    #pragma unroll
    for (int f = 0; f < 2; ++f)
        #pragma unroll
        for (int cf = 0; cf < 4; ++cf) acc[f][cf] = zero;
    f32x4 ls0 = zero, ls1 = zero;

    bf16x8 kf = *(const bf16x8*)(kTb + (size_t)(w * 16 + li) * CQ + 8 * g);
    for (int it = 0; it < 49; ++it) {
        const int jt = it * 64;
        f32x4 s0 = MFMA16(qf0, kf, zero);
        f32x4 s1 = MFMA16(qf1, kf, zero);
        unsigned char* Pb = P[it & 1];
        const int colb = (w * 16 + li) * 2;
        #pragma unroll
        for (int r = 0; r < 4; ++r) {
            int row0 = 4 * g + r;
            float p0 = __expf(s0[r] - mr0[r]); ls0[r] += p0;
            *(u16*)(Pb + ((row0 * 128 + colb) ^ ((row0 & 7) << 4))) = f2b(p0);
            int row1 = 16 + 4 * g + r;
            float p1 = __expf(s1[r] - mr1[r]); ls1[r] += p1;
            *(u16*)(Pb + ((row1 * 128 + colb) ^ ((row1 & 7) << 4))) = f2b(p1);
        }
        bf16x8 vf[2][4];
        #pragma unroll
        for (int ks = 0; ks < 2; ++ks)
            #pragma unroll
            for (int cf = 0; cf < 4; ++cf)
                vf[ks][cf] = *(const bf16x8*)(Vbb + (size_t)(w * 64 + cf * 16 + li) * N_SP
                                              + jt + ks * 32 + 8 * g);
        if (it < 48)
            kf = *(const bf16x8*)(kTb + (size_t)(jt + 64 + w * 16 + li) * CQ + 8 * g);
        __syncthreads();
        #pragma unroll
        for (int f = 0; f < 2; ++f) {
            const int rowr = f * 16 + li;
            const int swz = (rowr & 7) << 4;
            bf16x8 pa0 = *(const bf16x8*)(Pb + ((rowr * 128 + 16 * g) ^ swz));
            bf16x8 pa1 = *(const bf16x8*)(Pb + ((rowr * 128 + 64 + 16 * g) ^ swz));
            #pragma unroll
            for (int cf = 0; cf < 4; ++cf) {
                acc[f][cf] = MFMA16(pa0, vf[0][cf], acc[f][cf]);
                acc[f][cf] = MFMA16(pa1, vf[1][cf], acc[f][cf]);
            }
        }
    }

    // ---- row sums ----
    #pragma unroll
    for (int d = 1; d < 16; d <<= 1) {
        #pragma unroll
        for (int r = 0; r < 4; ++r) {
            ls0[r] += __shfl_xor(ls0[r], d);
            ls1[r] += __shfl_xor(ls1[r], d);
        }
    }
    if (li == 0) {
        #pragma unroll
        for (int r = 0; r < 4; ++r) {
            red_part[w][4 * g + r]      = ls0[r];
            red_part[w][16 + 4 * g + r] = ls1[r];
        }
    }
    __syncthreads();
    if (t < 32) red_final[t] = red_part[0][t] + red_part[1][t] + red_part[2][t] + red_part[3][t];
    __syncthreads();
    const f32x4 lf0 = *(const f32x4*)(red_final + 4 * g);
    const f32x4 lf1 = *(const f32x4*)(red_final + 16 + 4 * g);
    const float gm = gamma_p[0];

    f32x4 rinv0, rinv1;
    #pragma unroll
    for (int r = 0; r < 4; ++r) {
        rinv0[r] = gm * INV_BOUND / lf0[r];
        rinv1[r] = gm * INV_BOUND / lf1[r];
    }
    #pragma unroll
    for (int f = 0; f < 2; ++f) {
        const f32x4 rv = f ? rinv1 : rinv0;
        #pragma unroll
        for (int cf = 0; cf < 4; ++cf) {
            const int c = w * 64 + cf * 16 + li;
            const size_t base = (size_t)(b * C_CH + c) * N_SP + i0 + f * 16 + 4 * g;
            float4 xv = *(const float4*)(x + base);
            float4 o;
            o.x = acc[f][cf][0] * rv[0] + xv.x;
            o.y = acc[f][cf][1] * rv[1] + xv.y;
            o.z = acc[f][cf][2] * rv[2] + xv.z;
            o.w = acc[f][cf][3] * rv[3] + xv.w;
            *(float4*)(out + base) = o;
        }
    }
}

// ---------------------------------------------------------------------------
extern "C" void kernel_launch(void* const* d_in, const int* in_sizes, int n_in,
                              void* d_out, int out_size, void* d_ws, size_t ws_size,
                              hipStream_t stream)
{
    const float* x  = (const float*)d_in[0];
    const float* Wq = (const float*)d_in[1];
    const float* bq = (const float*)d_in[2];
    const float* Wk = (const float*)d_in[3];
    const float* bk = (const float*)d_in[4];
    const float* Wv = (const float*)d_in[5];
    const float* bv = (const float*)d_in[6];
    const float* gm = (const float*)d_in[7];
    float* out = (float*)d_out;

    // ws layout: scale(256B) | Wqb 16K | Wkb 16K | Wvb 128K | xT 6.42M | qT .8M | kT .8M | V 6.42M
    float* scale = (float*)d_ws;
    u16* Wqb = (u16*)((char*)d_ws + 256);
    u16* Wkb = Wqb + 32 * 256;
    u16* Wvb = Wkb + 32 * 256;
    u16* xT  = Wvb + 256 * 256;
    u16* qT  = xT + (size_t)NB * N_SP * C_CH;
    u16* kT  = qT + (size_t)NB * N_SP * CQ;
    u16* Vb  = kT + (size_t)NB * N_SP * CQ;

    norm_kernel<<<1, 256, 0, stream>>>(Wq, Wk, Wv, scale);
    wcvt_kernel<<<80, 256, 0, stream>>>(Wq, Wk, Wv, Wqb, Wkb, Wvb);
    xt_kernel<<<NB * 49 * 4, 256, 0, stream>>>(x, xT);
    qkv_mfma<<<NB * 49, 256, 0, stream>>>(xT, Wqb, Wkb, Wvb, bq, bk, bv, scale, qT, kT, Vb);
    attn_mfma<<<NB * 98, 256, 0, stream>>>(qT, kT, Vb, x, gm, out);
}

// Round 3
// 163.381 us; speedup vs baseline: 6.6409x; 1.0175x over previous
//
#include <hip/hip_runtime.h>

#define N_SP 3136   // H*W
#define C_CH 256
#define CQ   32
#define NB   4
// 1 / (exp(sqrt(3))*sqrt(3136/256) + 2*sqrt(6))
#define INV_BOUND 0.04051569f
#define LOG2E 1.44269504f

typedef __attribute__((ext_vector_type(8))) short bf16x8;
typedef __attribute__((ext_vector_type(4))) float f32x4;
typedef unsigned short u16;
typedef unsigned int   u32;

#define MFMA16(a,b,c) __builtin_amdgcn_mfma_f32_16x16x32_bf16(a,b,c,0,0,0)

__device__ __forceinline__ u16 f2b(float f) {
    u32 u = __builtin_bit_cast(u32, f);
    u += 0x7fffu + ((u >> 16) & 1u);   // RTNE
    return (u16)(u >> 16);
}

// ---------------------------------------------------------------------------
// stage1: fused xT transpose (blocks 0..783), W->bf16 (784..863), norm (864)
// ---------------------------------------------------------------------------
__global__ __launch_bounds__(256) void stage1_kernel(
    const float* __restrict__ x, const float* __restrict__ Wq,
    const float* __restrict__ Wk, const float* __restrict__ Wv,
    u16* __restrict__ xT, u16* __restrict__ Wqb, u16* __restrict__ Wkb,
    u16* __restrict__ Wvb, float* __restrict__ scale_out)
{
    __shared__ float smem[64 * 65];
    const int t = threadIdx.x;
    const int bid = blockIdx.x;

    if (bid < 784) {                       // xT[b][n][c] = bf16(x[b][c][n])
        float (*tile)[65] = (float(*)[65])smem;
        const int ct = bid & 3, nt = (bid >> 2) % 49, b = bid / 196;
        const int c0 = ct * 64, n0 = nt * 64;
        const int cc = t >> 4, nn4 = (t & 15) * 4;
        #pragma unroll
        for (int i = 0; i < 4; ++i) {
            int cl = cc + i * 16;
            float4 v = *(const float4*)(x + (size_t)(b * C_CH + c0 + cl) * N_SP + n0 + nn4);
            tile[cl][nn4] = v.x; tile[cl][nn4 + 1] = v.y;
            tile[cl][nn4 + 2] = v.z; tile[cl][nn4 + 3] = v.w;
        }
        __syncthreads();
        const int c4 = (t & 15) * 4, nn = t >> 4;
        #pragma unroll
        for (int i = 0; i < 4; ++i) {
            int nl = nn + i * 16;
            ushort4 o;
            o.x = f2b(tile[c4 + 0][nl]); o.y = f2b(tile[c4 + 1][nl]);
            o.z = f2b(tile[c4 + 2][nl]); o.w = f2b(tile[c4 + 3][nl]);
            *(ushort4*)(xT + (size_t)(b * N_SP + n0 + nl) * C_CH + c0 + c4) = o;
        }
    } else if (bid < 864) {                // W f32 -> bf16
        int idx = (bid - 784) * 256 + t;
        const float* src; u16* dst; int off;
        if (idx < 2048)      { src = Wq; dst = Wqb; off = idx; }
        else if (idx < 4096) { src = Wk; dst = Wkb; off = idx - 2048; }
        else                 { src = Wv; dst = Wvb; off = idx - 4096; }
        float4 v = *(const float4*)(src + off * 4);
        ushort4 o; o.x = f2b(v.x); o.y = f2b(v.y); o.z = f2b(v.z); o.w = f2b(v.w);
        *(ushort4*)(dst + off * 4) = o;
    } else {                               // norm -> scale
        float* red = smem;
        float u2 = 0.f;
        for (int i = t; i < CQ * C_CH; i += 256) { float w = Wq[i]; u2 += w * w; }
        red[t] = u2; __syncthreads();
        #pragma unroll
        for (int s = 128; s > 0; s >>= 1) { if (t < s) red[t] += red[t + s]; __syncthreads(); }
        float u2t = red[0]; __syncthreads();
        float vn2 = 0.f;
        for (int o = 0; o < CQ; ++o)   { float w = Wk[o * C_CH + t]; vn2 += w * w; }
        float wn2 = 0.f;
        for (int o = 0; o < C_CH; ++o) { float w = Wv[o * C_CH + t]; wn2 += w * w; }
        red[t] = fmaxf(vn2, wn2); __syncthreads();
        #pragma unroll
        for (int s = 128; s > 0; s >>= 1) { if (t < s) red[t] = fmaxf(red[t], red[t + s]); __syncthreads(); }
        if (t == 0) scale_out[0] = 1.0f / (sqrtf(u2t) * sqrtf(red[0]));
    }
}

// ---------------------------------------------------------------------------
// qkv via MFMA, 5-way row split (split0: q+k, split1..4: 64 V-rows each).
// Also emits qnorm[b][n] = ||scaled q row|| and kmax[b] = max_n ||k_n||.
// qT is pre-multiplied by scale*log2(e) so attention exp is a bare exp2.
// ---------------------------------------------------------------------------
__global__ __launch_bounds__(256) void qkv_mfma(
    const u16* __restrict__ xT, const u16* __restrict__ Wqb,
    const u16* __restrict__ Wkb, const u16* __restrict__ Wvb,
    const float* __restrict__ bq, const float* __restrict__ bk,
    const float* __restrict__ bv, const float* __restrict__ scale_p,
    u16* __restrict__ qT, u16* __restrict__ kT, u16* __restrict__ Vb,
    float* __restrict__ qnorm, float* __restrict__ kmax)
{
    const int t = threadIdx.x;
    const int split = blockIdx.x / 196, tile = blockIdx.x % 196;
    const int b = tile / 49, nt = tile % 49;
    const int w = t >> 6, li = t & 15, g = (t >> 4) & 3;
    const int n = nt * 64 + w * 16 + li;
    const f32x4 zero = {0.f, 0.f, 0.f, 0.f};

    bf16x8 xf[8];
    #pragma unroll
    for (int ks = 0; ks < 8; ++ks)
        xf[ks] = *(const bf16x8*)(xT + (size_t)(b * N_SP + n) * C_CH + ks * 32 + 8 * g);

    if (split == 0) {
        f32x4 aq0 = zero, aq1 = zero, ak0 = zero, ak1 = zero;
        #pragma unroll
        for (int ks = 0; ks < 8; ++ks) {
            bf16x8 w0 = *(const bf16x8*)(Wqb + li * C_CH + ks * 32 + 8 * g);
            bf16x8 w1 = *(const bf16x8*)(Wqb + (16 + li) * C_CH + ks * 32 + 8 * g);
            bf16x8 w2 = *(const bf16x8*)(Wkb + li * C_CH + ks * 32 + 8 * g);
            bf16x8 w3 = *(const bf16x8*)(Wkb + (16 + li) * C_CH + ks * 32 + 8 * g);
            aq0 = MFMA16(w0, xf[ks], aq0);
            aq1 = MFMA16(w1, xf[ks], aq1);
            ak0 = MFMA16(w2, xf[ks], ak0);
            ak1 = MFMA16(w3, xf[ks], ak1);
        }
        const float scf = scale_p[0] * LOG2E;
        f32x4 bq0 = *(const f32x4*)(bq + 4 * g);
        f32x4 bq1 = *(const f32x4*)(bq + 16 + 4 * g);
        f32x4 bk0 = *(const f32x4*)(bk + 4 * g);
        f32x4 bk1 = *(const f32x4*)(bk + 16 + 4 * g);
        float qn2 = 0.f, kn2 = 0.f;
        ushort4 s0, s1;
        #pragma unroll
        for (int r = 0; r < 4; ++r) {
            float q0 = (aq0[r] + bq0[r]) * scf;
            float q1 = (aq1[r] + bq1[r]) * scf;
            qn2 += q0 * q0 + q1 * q1;
            ((u16*)&s0)[r] = f2b(q0); ((u16*)&s1)[r] = f2b(q1);
        }
        *(ushort4*)(qT + (size_t)(b * N_SP + n) * CQ + 4 * g)      = s0;
        *(ushort4*)(qT + (size_t)(b * N_SP + n) * CQ + 16 + 4 * g) = s1;
        #pragma unroll
        for (int r = 0; r < 4; ++r) {
            float k0 = ak0[r] + bk0[r];
            float k1 = ak1[r] + bk1[r];
            kn2 += k0 * k0 + k1 * k1;
            ((u16*)&s0)[r] = f2b(k0); ((u16*)&s1)[r] = f2b(k1);
        }
        *(ushort4*)(kT + (size_t)(b * N_SP + n) * CQ + 4 * g)      = s0;
        *(ushort4*)(kT + (size_t)(b * N_SP + n) * CQ + 16 + 4 * g) = s1;

        qn2 += __shfl_xor(qn2, 16); qn2 += __shfl_xor(qn2, 32);
        kn2 += __shfl_xor(kn2, 16); kn2 += __shfl_xor(kn2, 32);
        if (g == 0) qnorm[b * N_SP + n] = sqrtf(qn2);
        float kn = sqrtf(kn2);
        #pragma unroll
        for (int d = 1; d < 16; d <<= 1) kn = fmaxf(kn, __shfl_xor(kn, d));
        if ((t & 63) == 0) atomicMax((int*)(kmax + b), __float_as_int(kn));
    } else {
        const int r0 = (split - 1) * 64;
        f32x4 a[4] = {zero, zero, zero, zero};
        #pragma unroll
        for (int ks = 0; ks < 8; ++ks) {
            #pragma unroll
            for (int fr = 0; fr < 4; ++fr) {
                bf16x8 wf = *(const bf16x8*)(Wvb + (size_t)(r0 + fr * 16 + li) * C_CH + ks * 32 + 8 * g);
                a[fr] = MFMA16(wf, xf[ks], a[fr]);
            }
        }
        #pragma unroll
        for (int fr = 0; fr < 4; ++fr) {
            f32x4 bb = *(const f32x4*)(bv + r0 + fr * 16 + 4 * g);
            #pragma unroll
            for (int r = 0; r < 4; ++r)
                Vb[(size_t)(b * C_CH + r0 + fr * 16 + 4 * g + r) * N_SP + n] = f2b(a[fr][r] + bb[r]);
        }
    }
}

// ---------------------------------------------------------------------------
// Single-pass attention, channel-split. Block = 32 q x 64 ch; 4 waves, each
// wave owns 32-j stripes (no barrier in main loop: P write/read is same-wave).
// p = exp2(S - qnorm_i*kmax) (Cauchy-Schwarz bound, exact via shift-invariance)
// ---------------------------------------------------------------------------
__global__ __launch_bounds__(256) void attn_mfma(
    const u16* __restrict__ qT, const u16* __restrict__ kT,
    const u16* __restrict__ Vb, const float* __restrict__ x,
    const float* __restrict__ gamma_p, const float* __restrict__ qnorm,
    const float* __restrict__ kmax, float* __restrict__ out)
{
    __shared__ __align__(16) u16 P[4][32][40];       // stride 80 B: 2-way banks
    __shared__ __align__(16) float accL[2][32][64];  // 16 KB cross-wave reduce
    __shared__ float red_part[4][32];
    __shared__ __align__(16) float red_final[32];

    const int t = threadIdx.x;
    const int w = t >> 6, li = t & 15, g = (t >> 4) & 3;
    const int bid = blockIdx.x;
    const int xcd = bid & 7, idx = bid >> 3;         // 1568 = 8 * 196, bijective
    const int grp = 2 * xcd + (idx >= 98 ? 1 : 0);
    const int within = idx >= 98 ? idx - 98 : idx;
    const int b = grp >> 2, cs = grp & 3;
    const int i0 = within * 32;

    const u16* qTb = qT + (size_t)b * N_SP * CQ;
    const u16* kTb = kT + (size_t)b * N_SP * CQ;
    const u16* Vbb = Vb + ((size_t)b * C_CH + cs * 64) * N_SP;
    const float kmb = kmax[b];
    const f32x4 zero = {0.f, 0.f, 0.f, 0.f};

    const bf16x8 qf0 = *(const bf16x8*)(qTb + (size_t)(i0 + li) * CQ + 8 * g);
    const bf16x8 qf1 = *(const bf16x8*)(qTb + (size_t)(i0 + 16 + li) * CQ + 8 * g);
    f32x4 mr0, mr1;
    #pragma unroll
    for (int r = 0; r < 4; ++r) {
        mr0[r] = qnorm[b * N_SP + i0 + 4 * g + r] * kmb;
        mr1[r] = qnorm[b * N_SP + i0 + 16 + 4 * g + r] * kmb;
    }

    f32x4 acc[2][4];
    #pragma unroll
    for (int f = 0; f < 2; ++f)
        #pragma unroll
        for (int cf = 0; cf < 4; ++cf) acc[f][cf] = zero;
    f32x4 ls0 = zero, ls1 = zero;

    for (int s = w; s < 98; s += 4) {
        const int j0 = s * 32;
        bf16x8 kf0 = *(const bf16x8*)(kTb + (size_t)(j0 + li) * CQ + 8 * g);
        bf16x8 kf1 = *(const bf16x8*)(kTb + (size_t)(j0 + 16 + li) * CQ + 8 * g);
        f32x4 s00 = MFMA16(qf0, kf0, zero);
        f32x4 s01 = MFMA16(qf0, kf1, zero);
        f32x4 s10 = MFMA16(qf1, kf0, zero);
        f32x4 s11 = MFMA16(qf1, kf1, zero);
        bf16x8 vf0 = *(const bf16x8*)(Vbb + (size_t)(0 * 16 + li) * N_SP + j0 + 8 * g);
        bf16x8 vf1 = *(const bf16x8*)(Vbb + (size_t)(1 * 16 + li) * N_SP + j0 + 8 * g);
        bf16x8 vf2 = *(const bf16x8*)(Vbb + (size_t)(2 * 16 + li) * N_SP + j0 + 8 * g);
        bf16x8 vf3 = *(const bf16x8*)(Vbb + (size_t)(3 * 16 + li) * N_SP + j0 + 8 * g);
        #pragma unroll
        for (int r = 0; r < 4; ++r) {
            float p00 = exp2f(s00[r] - mr0[r]); ls0[r] += p00;
            float p01 = exp2f(s01[r] - mr0[r]); ls0[r] += p01;
            float p10 = exp2f(s10[r] - mr1[r]); ls1[r] += p10;
            float p11 = exp2f(s11[r] - mr1[r]); ls1[r] += p11;
            P[w][4 * g + r][li]           = f2b(p00);
            P[w][4 * g + r][16 + li]      = f2b(p01);
            P[w][16 + 4 * g + r][li]      = f2b(p10);
            P[w][16 + 4 * g + r][16 + li] = f2b(p11);
        }
        bf16x8 pa0 = *(const bf16x8*)&P[w][li][8 * g];
        bf16x8 pa1 = *(const bf16x8*)&P[w][16 + li][8 * g];
        acc[0][0] = MFMA16(pa0, vf0, acc[0][0]);
        acc[0][1] = MFMA16(pa0, vf1, acc[0][1]);
        acc[0][2] = MFMA16(pa0, vf2, acc[0][2]);
        acc[0][3] = MFMA16(pa0, vf3, acc[0][3]);
        acc[1][0] = MFMA16(pa1, vf0, acc[1][0]);
        acc[1][1] = MFMA16(pa1, vf1, acc[1][1]);
        acc[1][2] = MFMA16(pa1, vf2, acc[1][2]);
        acc[1][3] = MFMA16(pa1, vf3, acc[1][3]);
    }

    // ---- reductions: ls over 16 lanes, then acc+ls across waves ----
    #pragma unroll
    for (int d = 1; d < 16; d <<= 1) {
        #pragma unroll
        for (int r = 0; r < 4; ++r) {
            ls0[r] += __shfl_xor(ls0[r], d);
            ls1[r] += __shfl_xor(ls1[r], d);
        }
    }
    if (li == 0) {
        #pragma unroll
        for (int r = 0; r < 4; ++r) {
            red_part[w][4 * g + r]      = ls0[r];
            red_part[w][16 + 4 * g + r] = ls1[r];
        }
    }
    if (w >= 2) {
        #pragma unroll
        for (int f = 0; f < 2; ++f)
            #pragma unroll
            for (int cf = 0; cf < 4; ++cf)
                #pragma unroll
                for (int r = 0; r < 4; ++r)
                    accL[w - 2][f * 16 + 4 * g + r][cf * 16 + li] = acc[f][cf][r];
    }
    __syncthreads();
    if (w < 2) {
        #pragma unroll
        for (int f = 0; f < 2; ++f)
            #pragma unroll
            for (int cf = 0; cf < 4; ++cf)
                #pragma unroll
                for (int r = 0; r < 4; ++r)
                    acc[f][cf][r] += accL[w][f * 16 + 4 * g + r][cf * 16 + li];
    }
    if (t < 32) red_final[t] = red_part[0][t] + red_part[1][t] + red_part[2][t] + red_part[3][t];
    __syncthreads();
    if (w == 1) {
        #pragma unroll
        for (int f = 0; f < 2; ++f)
            #pragma unroll
            for (int cf = 0; cf < 4; ++cf)
                #pragma unroll
                for (int r = 0; r < 4; ++r)
                    accL[1][f * 16 + 4 * g + r][cf * 16 + li] = acc[f][cf][r];
    }
    __syncthreads();
    if (w == 0) {
        const float gm = gamma_p[0];
        f32x4 lf0 = *(const f32x4*)(red_final + 4 * g);
        f32x4 lf1 = *(const f32x4*)(red_final + 16 + 4 * g);
        f32x4 rinv0, rinv1;
        #pragma unroll
        for (int r = 0; r < 4; ++r) {
            rinv0[r] = gm * INV_BOUND / lf0[r];
            rinv1[r] = gm * INV_BOUND / lf1[r];
        }
        #pragma unroll
        for (int f = 0; f < 2; ++f) {
            const f32x4 rv = f ? rinv1 : rinv0;
            #pragma unroll
            for (int cf = 0; cf < 4; ++cf) {
                const int c = cs * 64 + cf * 16 + li;
                const size_t base = ((size_t)b * C_CH + c) * N_SP + i0 + f * 16 + 4 * g;
                float4 xv = *(const float4*)(x + base);
                float4 o;
                float a0 = acc[f][cf][0] + accL[1][f * 16 + 4 * g + 0][cf * 16 + li];
                float a1 = acc[f][cf][1] + accL[1][f * 16 + 4 * g + 1][cf * 16 + li];
                float a2 = acc[f][cf][2] + accL[1][f * 16 + 4 * g + 2][cf * 16 + li];
                float a3 = acc[f][cf][3] + accL[1][f * 16 + 4 * g + 3][cf * 16 + li];
                o.x = a0 * rv[0] + xv.x;
                o.y = a1 * rv[1] + xv.y;
                o.z = a2 * rv[2] + xv.z;
                o.w = a3 * rv[3] + xv.w;
                *(float4*)(out + base) = o;
            }
        }
    }
}

// ---------------------------------------------------------------------------
extern "C" void kernel_launch(void* const* d_in, const int* in_sizes, int n_in,
                              void* d_out, int out_size, void* d_ws, size_t ws_size,
                              hipStream_t stream)
{
    const float* x  = (const float*)d_in[0];
    const float* Wq = (const float*)d_in[1];
    const float* bq = (const float*)d_in[2];
    const float* Wk = (const float*)d_in[3];
    const float* bk = (const float*)d_in[4];
    const float* Wv = (const float*)d_in[5];
    const float* bv = (const float*)d_in[6];
    const float* gm = (const float*)d_in[7];
    float* out = (float*)d_out;
    float* ws  = (float*)d_ws;

    float* scale = ws;                       // [0..3]
    float* kmax  = ws + 4;                   // [4..7], per-batch
    float* qnorm = ws + 8;                   // NB*N_SP floats
    u16* Wqb = (u16*)(ws + 8 + NB * N_SP);   // 16-byte aligned (50208 % 16 == 0)
    u16* Wkb = Wqb + 32 * 256;
    u16* Wvb = Wkb + 32 * 256;
    u16* xT  = Wvb + 256 * 256;
    u16* qT  = xT + (size_t)NB * N_SP * C_CH;
    u16* kT  = qT + (size_t)NB * N_SP * CQ;
    u16* Vb  = kT + (size_t)NB * N_SP * CQ;

    hipMemsetAsync(kmax, 0, NB * sizeof(float), stream);
    stage1_kernel<<<865, 256, 0, stream>>>(x, Wq, Wk, Wv, xT, Wqb, Wkb, Wvb, scale);
    qkv_mfma<<<980, 256, 0, stream>>>(xT, Wqb, Wkb, Wvb, bq, bk, bv, scale, qT, kT, Vb, qnorm, kmax);
    attn_mfma<<<1568, 256, 0, stream>>>(qT, kT, Vb, x, gm, qnorm, kmax, out);
}

// Round 5
// 161.793 us; speedup vs baseline: 6.7061x; 1.0098x over previous
//
#include <hip/hip_runtime.h>

#define N_SP 3136   // H*W
#define C_CH 256
#define CQ   32
#define NB   4
// 1 / (exp(sqrt(3))*sqrt(3136/256) + 2*sqrt(6))
#define INV_BOUND 0.04051569f
#define LOG2E 1.44269504f

typedef __attribute__((ext_vector_type(8))) short bf16x8;
typedef __attribute__((ext_vector_type(4))) float f32x4;
typedef __attribute__((ext_vector_type(2))) unsigned int u32x2;
typedef unsigned short u16;
typedef unsigned int   u32;

#define MFMA16(a,b,c) __builtin_amdgcn_mfma_f32_16x16x32_bf16(a,b,c,0,0,0)

__device__ __forceinline__ u16 f2b(float f) {
    u32 u = __builtin_bit_cast(u32, f);
    u += 0x7fffu + ((u >> 16) & 1u);   // RTNE
    return (u16)(u >> 16);
}
__device__ __forceinline__ u32 pk_bf16(float a, float b) {
    return (u32)f2b(a) | ((u32)f2b(b) << 16);
}

// ---------------------------------------------------------------------------
// stage1: fused xT transpose (blocks 0..783), W->bf16 (784..863), norm (864)
// ---------------------------------------------------------------------------
__global__ __launch_bounds__(256) void stage1_kernel(
    const float* __restrict__ x, const float* __restrict__ Wq,
    const float* __restrict__ Wk, const float* __restrict__ Wv,
    u16* __restrict__ xT, u16* __restrict__ Wqb, u16* __restrict__ Wkb,
    u16* __restrict__ Wvb, float* __restrict__ scale_out)
{
    __shared__ float smem[64 * 65];
    const int t = threadIdx.x;
    const int bid = blockIdx.x;

    if (bid < 784) {                       // xT[b][n][c] = bf16(x[b][c][n])
        float (*tile)[65] = (float(*)[65])smem;
        const int ct = bid & 3, nt = (bid >> 2) % 49, b = bid / 196;
        const int c0 = ct * 64, n0 = nt * 64;
        const int cc = t >> 4, nn4 = (t & 15) * 4;
        #pragma unroll
        for (int i = 0; i < 4; ++i) {
            int cl = cc + i * 16;
            float4 v = *(const float4*)(x + (size_t)(b * C_CH + c0 + cl) * N_SP + n0 + nn4);
            tile[cl][nn4] = v.x; tile[cl][nn4 + 1] = v.y;
            tile[cl][nn4 + 2] = v.z; tile[cl][nn4 + 3] = v.w;
        }
        __syncthreads();
        const int c4 = (t & 15) * 4, nn = t >> 4;
        #pragma unroll
        for (int i = 0; i < 4; ++i) {
            int nl = nn + i * 16;
            ushort4 o;
            o.x = f2b(tile[c4 + 0][nl]); o.y = f2b(tile[c4 + 1][nl]);
            o.z = f2b(tile[c4 + 2][nl]); o.w = f2b(tile[c4 + 3][nl]);
            *(ushort4*)(xT + (size_t)(b * N_SP + n0 + nl) * C_CH + c0 + c4) = o;
        }
    } else if (bid < 864) {                // W f32 -> bf16
        int idx = (bid - 784) * 256 + t;
        const float* src; u16* dst; int off;
        if (idx < 2048)      { src = Wq; dst = Wqb; off = idx; }
        else if (idx < 4096) { src = Wk; dst = Wkb; off = idx - 2048; }
        else                 { src = Wv; dst = Wvb; off = idx - 4096; }
        float4 v = *(const float4*)(src + off * 4);
        ushort4 o; o.x = f2b(v.x); o.y = f2b(v.y); o.z = f2b(v.z); o.w = f2b(v.w);
        *(ushort4*)(dst + off * 4) = o;
    } else {                               // norm -> scale
        float* red = smem;
        float u2 = 0.f;
        for (int i = t; i < CQ * C_CH; i += 256) { float w = Wq[i]; u2 += w * w; }
        red[t] = u2; __syncthreads();
        #pragma unroll
        for (int s = 128; s > 0; s >>= 1) { if (t < s) red[t] += red[t + s]; __syncthreads(); }
        float u2t = red[0]; __syncthreads();
        float vn2 = 0.f;
        for (int o = 0; o < CQ; ++o)   { float w = Wk[o * C_CH + t]; vn2 += w * w; }
        float wn2 = 0.f;
        for (int o = 0; o < C_CH; ++o) { float w = Wv[o * C_CH + t]; wn2 += w * w; }
        red[t] = fmaxf(vn2, wn2); __syncthreads();
        #pragma unroll
        for (int s = 128; s > 0; s >>= 1) { if (t < s) red[t] = fmaxf(red[t], red[t + s]); __syncthreads(); }
        if (t == 0) scale_out[0] = 1.0f / (sqrtf(u2t) * sqrtf(red[0]));
    }
}

// ---------------------------------------------------------------------------
// qkv via MFMA, 5-way row split (split0: q+k, split1..4: 64 V-rows each).
// qT pre-multiplied by scale*log2(e); emits qnorm[b][n], kmax[b] (atomicMax).
// ---------------------------------------------------------------------------
__global__ __launch_bounds__(256) void qkv_mfma(
    const u16* __restrict__ xT, const u16* __restrict__ Wqb,
    const u16* __restrict__ Wkb, const u16* __restrict__ Wvb,
    const float* __restrict__ bq, const float* __restrict__ bk,
    const float* __restrict__ bv, const float* __restrict__ scale_p,
    u16* __restrict__ qT, u16* __restrict__ kT, u16* __restrict__ Vb,
    float* __restrict__ qnorm, float* __restrict__ kmax)
{
    const int t = threadIdx.x;
    const int split = blockIdx.x / 196, tile = blockIdx.x % 196;
    const int b = tile / 49, nt = tile % 49;
    const int w = t >> 6, li = t & 15, g = (t >> 4) & 3;
    const int n = nt * 64 + w * 16 + li;
    const f32x4 zero = {0.f, 0.f, 0.f, 0.f};

    bf16x8 xf[8];
    #pragma unroll
    for (int ks = 0; ks < 8; ++ks)
        xf[ks] = *(const bf16x8*)(xT + (size_t)(b * N_SP + n) * C_CH + ks * 32 + 8 * g);

    if (split == 0) {
        f32x4 aq0 = zero, aq1 = zero, ak0 = zero, ak1 = zero;
        #pragma unroll
        for (int ks = 0; ks < 8; ++ks) {
            bf16x8 w0 = *(const bf16x8*)(Wqb + li * C_CH + ks * 32 + 8 * g);
            bf16x8 w1 = *(const bf16x8*)(Wqb + (16 + li) * C_CH + ks * 32 + 8 * g);
            bf16x8 w2 = *(const bf16x8*)(Wkb + li * C_CH + ks * 32 + 8 * g);
            bf16x8 w3 = *(const bf16x8*)(Wkb + (16 + li) * C_CH + ks * 32 + 8 * g);
            aq0 = MFMA16(w0, xf[ks], aq0);
            aq1 = MFMA16(w1, xf[ks], aq1);
            ak0 = MFMA16(w2, xf[ks], ak0);
            ak1 = MFMA16(w3, xf[ks], ak1);
        }
        const float scf = scale_p[0] * LOG2E;
        f32x4 bq0 = *(const f32x4*)(bq + 4 * g);
        f32x4 bq1 = *(const f32x4*)(bq + 16 + 4 * g);
        f32x4 bk0 = *(const f32x4*)(bk + 4 * g);
        f32x4 bk1 = *(const f32x4*)(bk + 16 + 4 * g);
        float qn2 = 0.f, kn2 = 0.f;
        ushort4 s0, s1;
        #pragma unroll
        for (int r = 0; r < 4; ++r) {
            float q0 = (aq0[r] + bq0[r]) * scf;
            float q1 = (aq1[r] + bq1[r]) * scf;
            qn2 += q0 * q0 + q1 * q1;
            ((u16*)&s0)[r] = f2b(q0); ((u16*)&s1)[r] = f2b(q1);
        }
        *(ushort4*)(qT + (size_t)(b * N_SP + n) * CQ + 4 * g)      = s0;
        *(ushort4*)(qT + (size_t)(b * N_SP + n) * CQ + 16 + 4 * g) = s1;
        #pragma unroll
        for (int r = 0; r < 4; ++r) {
            float k0 = ak0[r] + bk0[r];
            float k1 = ak1[r] + bk1[r];
            kn2 += k0 * k0 + k1 * k1;
            ((u16*)&s0)[r] = f2b(k0); ((u16*)&s1)[r] = f2b(k1);
        }
        *(ushort4*)(kT + (size_t)(b * N_SP + n) * CQ + 4 * g)      = s0;
        *(ushort4*)(kT + (size_t)(b * N_SP + n) * CQ + 16 + 4 * g) = s1;

        qn2 += __shfl_xor(qn2, 16); qn2 += __shfl_xor(qn2, 32);
        kn2 += __shfl_xor(kn2, 16); kn2 += __shfl_xor(kn2, 32);
        if (g == 0) qnorm[b * N_SP + n] = sqrtf(qn2);
        float kn = sqrtf(kn2);
        #pragma unroll
        for (int d = 1; d < 16; d <<= 1) kn = fmaxf(kn, __shfl_xor(kn, d));
        if ((t & 63) == 0) atomicMax((int*)(kmax + b), __float_as_int(kn));
    } else {
        const int r0 = (split - 1) * 64;
        f32x4 a[4] = {zero, zero, zero, zero};
        #pragma unroll
        for (int ks = 0; ks < 8; ++ks) {
            #pragma unroll
            for (int fr = 0; fr < 4; ++fr) {
                bf16x8 wf = *(const bf16x8*)(Wvb + (size_t)(r0 + fr * 16 + li) * C_CH + ks * 32 + 8 * g);
                a[fr] = MFMA16(wf, xf[ks], a[fr]);
            }
        }
        #pragma unroll
        for (int fr = 0; fr < 4; ++fr) {
            f32x4 bb = *(const f32x4*)(bv + r0 + fr * 16 + 4 * g);
            #pragma unroll
            for (int r = 0; r < 4; ++r)
                Vb[(size_t)(b * C_CH + r0 + fr * 16 + 4 * g + r) * N_SP + n] = f2b(a[fr][r] + bb[r]);
        }
    }
}

// ---------------------------------------------------------------------------
// Attention: 392 blocks x 512 thr (8 waves). Block = 32 q x 256 ch x all j.
// Wave w: S^T slice (jq=w&3 16-j quarter, qf=w>>2 16-q half) -> packed b64
// writes into XOR-swizzled P; PV slice = 32 ch (cw=32w), both q-frags.
// One barrier/tile, double-buffered P. exp bound = qnorm*kmax (C-S, exact).
// ---------------------------------------------------------------------------
__global__ __launch_bounds__(512, 4) void attn_mfma(
    const u16* __restrict__ qT, const u16* __restrict__ kT,
    const u16* __restrict__ Vb, const float* __restrict__ x,
    const float* __restrict__ gamma_p, const float* __restrict__ qnorm,
    const float* __restrict__ kmax, float* __restrict__ out)
{
    __shared__ __align__(16) unsigned char P[2][32 * 128];   // 8 KB, swizzled
    __shared__ float red[8][16];
    __shared__ __align__(16) float red_final[32];

    const int t = threadIdx.x;
    const int w = t >> 6, li = t & 15, g = (t >> 4) & 3;
    const int qf = w >> 2, jq = w & 3;       // S assignment
    const int cw = w * 32;                   // PV channel base
    const int sw = (li & 7) << 4;            // XOR swizzle bits

    const int xcd = blockIdx.x & 7, idx = blockIdx.x >> 3;   // 392 = 8*49
    const int b  = xcd >> 1;
    const int i0 = ((xcd & 1) * 49 + idx) * 32;

    const u16* qTb = qT + (size_t)b * N_SP * CQ;
    const u16* kTb = kT + (size_t)b * N_SP * CQ;
    const u16* Vbb = Vb + (size_t)b * C_CH * N_SP;
    const f32x4 zero = {0.f, 0.f, 0.f, 0.f};

    const bf16x8 qfS = *(const bf16x8*)(qTb + (size_t)(i0 + qf * 16 + li) * CQ + 8 * g);
    const float  mrS = qnorm[b * N_SP + i0 + qf * 16 + li] * kmax[b];

    // LDS byte offsets
    const int pwOff  = (qf * 16 + li) * 128 + ((jq * 32 + 8 * g) ^ sw);  // b64 write
    const int prRow0 = li * 128, prRow1 = (16 + li) * 128;               // b128 reads

    f32x4 acc[2][2];
    acc[0][0] = zero; acc[0][1] = zero; acc[1][0] = zero; acc[1][1] = zero;
    float ls = 0.f;

    // prefetch tile 0
    bf16x8 kf = *(const bf16x8*)(kTb + (size_t)(jq * 16 + li) * CQ + 8 * g);
    bf16x8 vf0a = *(const bf16x8*)(Vbb + (size_t)(cw + li) * N_SP + 8 * g);
    bf16x8 vf0b = *(const bf16x8*)(Vbb + (size_t)(cw + li) * N_SP + 32 + 8 * g);
    bf16x8 vf1a = *(const bf16x8*)(Vbb + (size_t)(cw + 16 + li) * N_SP + 8 * g);
    bf16x8 vf1b = *(const bf16x8*)(Vbb + (size_t)(cw + 16 + li) * N_SP + 32 + 8 * g);

    #pragma unroll 2
    for (int it = 0; it < 49; ++it) {
        const int j0 = it * 64;
        // ---- S^T for this wave's (jq, qf) slice ----
        f32x4 s = MFMA16(kf, qfS, zero);
        if (it < 48)
            kf = *(const bf16x8*)(kTb + (size_t)(j0 + 64 + jq * 16 + li) * CQ + 8 * g);
        float p0 = exp2f(s[0] - mrS);
        float p1 = exp2f(s[1] - mrS);
        float p2 = exp2f(s[2] - mrS);
        float p3 = exp2f(s[3] - mrS);
        ls += (p0 + p1) + (p2 + p3);
        u32x2 pk; pk.x = pk_bf16(p0, p1); pk.y = pk_bf16(p2, p3);
        unsigned char* Pb = P[it & 1];
        *(u32x2*)(Pb + pwOff) = pk;
        __syncthreads();
        // ---- PV: this wave's 32 ch x 64 j, both q-frags ----
        bf16x8 nv0a, nv0b, nv1a, nv1b;
        if (it < 48) {
            nv0a = *(const bf16x8*)(Vbb + (size_t)(cw + li) * N_SP + j0 + 64 + 8 * g);
            nv0b = *(const bf16x8*)(Vbb + (size_t)(cw + li) * N_SP + j0 + 96 + 8 * g);
            nv1a = *(const bf16x8*)(Vbb + (size_t)(cw + 16 + li) * N_SP + j0 + 64 + 8 * g);
            nv1b = *(const bf16x8*)(Vbb + (size_t)(cw + 16 + li) * N_SP + j0 + 96 + 8 * g);
        }
        {   // ks = 0
            const int o = (16 * g) ^ sw;
            bf16x8 pa0 = *(const bf16x8*)(Pb + prRow0 + o);
            bf16x8 pa1 = *(const bf16x8*)(Pb + prRow1 + o);
            acc[0][0] = MFMA16(pa0, vf0a, acc[0][0]);
            acc[0][1] = MFMA16(pa0, vf1a, acc[0][1]);
            acc[1][0] = MFMA16(pa1, vf0a, acc[1][0]);
            acc[1][1] = MFMA16(pa1, vf1a, acc[1][1]);
        }
        {   // ks = 1
            const int o = (64 + 16 * g) ^ sw;
            bf16x8 pa0 = *(const bf16x8*)(Pb + prRow0 + o);
            bf16x8 pa1 = *(const bf16x8*)(Pb + prRow1 + o);
            acc[0][0] = MFMA16(pa0, vf0b, acc[0][0]);
            acc[0][1] = MFMA16(pa0, vf1b, acc[0][1]);
            acc[1][0] = MFMA16(pa1, vf0b, acc[1][0]);
            acc[1][1] = MFMA16(pa1, vf1b, acc[1][1]);
        }
        vf0a = nv0a; vf0b = nv0b; vf1a = nv1a; vf1b = nv1b;
    }

    // ---- denominator reduce: ls[q] over g (shfl) then jq waves (LDS) ----
    ls += __shfl_xor(ls, 16); ls += __shfl_xor(ls, 32);
    if ((t & 63) < 16) red[w][li] = ls;
    __syncthreads();
    if (t < 32)
        red_final[t] = red[(t >> 4) * 4 + 0][t & 15] + red[(t >> 4) * 4 + 1][t & 15]
                     + red[(t >> 4) * 4 + 2][t & 15] + red[(t >> 4) * 4 + 3][t & 15];
    __syncthreads();

    // ---- epilogue: /ls, *gamma*INV_BOUND, + residual ----
    const float gsc = gamma_p[0] * INV_BOUND;
    #pragma unroll
    for (int qi = 0; qi < 2; ++qi) {
        f32x4 lsv = *(const f32x4*)(red_final + qi * 16 + 4 * g);
        f32x4 rinv;
        #pragma unroll
        for (int r = 0; r < 4; ++r) rinv[r] = gsc / lsv[r];
        #pragma unroll
        for (int cf = 0; cf < 2; ++cf) {
            const int c = cw + cf * 16 + li;
            const size_t base = ((size_t)b * C_CH + c) * N_SP + i0 + qi * 16 + 4 * g;
            float4 xv = *(const float4*)(x + base);
            float4 o;
            o.x = acc[qi][cf][0] * rinv[0] + xv.x;
            o.y = acc[qi][cf][1] * rinv[1] + xv.y;
            o.z = acc[qi][cf][2] * rinv[2] + xv.z;
            o.w = acc[qi][cf][3] * rinv[3] + xv.w;
            *(float4*)(out + base) = o;
        }
    }
}

// ---------------------------------------------------------------------------
extern "C" void kernel_launch(void* const* d_in, const int* in_sizes, int n_in,
                              void* d_out, int out_size, void* d_ws, size_t ws_size,
                              hipStream_t stream)
{
    const float* x  = (const float*)d_in[0];
    const float* Wq = (const float*)d_in[1];
    const float* bq = (const float*)d_in[2];
    const float* Wk = (const float*)d_in[3];
    const float* bk = (const float*)d_in[4];
    const float* Wv = (const float*)d_in[5];
    const float* bv = (const float*)d_in[6];
    const float* gm = (const float*)d_in[7];
    float* out = (float*)d_out;
    float* ws  = (float*)d_ws;

    float* scale = ws;                       // [0..3]
    float* kmax  = ws + 4;                   // [4..7], per-batch
    float* qnorm = ws + 8;                   // NB*N_SP floats
    u16* Wqb = (u16*)(ws + 8 + NB * N_SP);   // 16B-aligned (50208 % 16 == 0)
    u16* Wkb = Wqb + 32 * 256;
    u16* Wvb = Wkb + 32 * 256;
    u16* xT  = Wvb + 256 * 256;
    u16* qT  = xT + (size_t)NB * N_SP * C_CH;
    u16* kT  = qT + (size_t)NB * N_SP * CQ;
    u16* Vb  = kT + (size_t)NB * N_SP * CQ;

    (void)hipMemsetAsync(kmax, 0, NB * sizeof(float), stream);
    stage1_kernel<<<865, 256, 0, stream>>>(x, Wq, Wk, Wv, xT, Wqb, Wkb, Wvb, scale);
    qkv_mfma<<<980, 256, 0, stream>>>(xT, Wqb, Wkb, Wvb, bq, bk, bv, scale, qT, kT, Vb, qnorm, kmax);
    attn_mfma<<<392, 512, 0, stream>>>(qT, kT, Vb, x, gm, qnorm, kmax, out);
}